// Round 4
// baseline (118.451 us; speedup 1.0000x reference)
//
#include <hip/hip_runtime.h>
#include <hip/hip_bf16.h>
#include <stdint.h>

typedef float f32x4 __attribute__((ext_vector_type(4)));
typedef __bf16 bf16x8 __attribute__((ext_vector_type(8)));

#define T_SEQ 2048
#define D_EMB 1024
#define H_DIM 128
#define NBATCH 8
#define NTOK 16384  // NBATCH * T_SEQ

typedef __attribute__((address_space(3))) uint32_t lds_u32;
typedef const __attribute__((address_space(1))) uint32_t glb_u32;

// ---------------------------------------------------------------------------
// ws layout (bf16 elements):
//   Wt : [3][128][1024]   transposed weights (W^T), q|k|v
//   qb : [16384][128]     Q bf16
//   kb : [16384][128]     K bf16
//   vt : [8][128][2048]   V transposed per batch (PV B-frags contiguous)
// ---------------------------------------------------------------------------

__global__ __launch_bounds__(256) void prep_w_kernel(
    const float* __restrict__ Wq, const float* __restrict__ Wk,
    const float* __restrict__ Wv, __hip_bfloat16* __restrict__ Wt) {
  const int mat = blockIdx.x >> 7;   // 0..2
  const int h = blockIdx.x & 127;
  const float* W = (mat == 0) ? Wq : ((mat == 1) ? Wk : Wv);
  __hip_bfloat16* dst = Wt + (size_t)(mat * 128 + h) * D_EMB;
  for (int k = threadIdx.x; k < D_EMB; k += 256)
    dst[k] = __float2bfloat16(W[(size_t)k * H_DIM + h]);
}

// Projection GEMM, m97-style: C[16384,384] = xb * Wt^T.
// BM=64 x BN=384 (full N -> x read exactly once) x BK=64.
__global__ __launch_bounds__(512) void proj_kernel(
    const float* __restrict__ x, const __hip_bfloat16* __restrict__ Wt,
    __hip_bfloat16* __restrict__ qb, __hip_bfloat16* __restrict__ kb,
    __hip_bfloat16* __restrict__ vt) {
  __shared__ __align__(16) __hip_bfloat16 As[64 * 64];    // 8 KB
  __shared__ __align__(16) __hip_bfloat16 Bs[384 * 64];   // 48 KB
  const int tid = threadIdx.x;
  const int wave = tid >> 6;
  const int lane = tid & 63;
  const int g = lane >> 4;
  const int lr = lane & 15;
  const int m0 = blockIdx.x * 64;
  const int wc = wave * 48;

  f32x4 acc[4][3];
#pragma unroll
  for (int m = 0; m < 4; ++m)
#pragma unroll
    for (int n = 0; n < 3; ++n) acc[m][n] = f32x4{0.f, 0.f, 0.f, 0.f};

  const int arow = tid >> 3;        // 0..63
  const int acol = (tid & 7) * 8;   // 0..56
  const float* asrc = x + (size_t)(m0 + arow) * D_EMB + acol;
  __hip_bfloat16* adst = &As[arow * 64 + (acol ^ ((arow & 7) * 8))];

  for (int k0 = 0; k0 < D_EMB; k0 += 64) {
    __syncthreads();
#pragma unroll
    for (int i = 0; i < 6; ++i) {
      const int e = (i * 512 + tid) * 8;   // bf16 element index
      const int br = e >> 6;
      const int bc = e & 63;
      __builtin_amdgcn_global_load_lds(
          (glb_u32*)(uintptr_t)(Wt + (size_t)br * D_EMB + k0 + bc),
          (lds_u32*)(uintptr_t)(&Bs[e]), 16, 0, 0);
    }
    {
      const float4 f0 = *reinterpret_cast<const float4*>(asrc + k0);
      const float4 f1 = *reinterpret_cast<const float4*>(asrc + k0 + 4);
      union { bf16x8 v; __hip_bfloat16 h[8]; } u;
      u.h[0] = __float2bfloat16(f0.x);
      u.h[1] = __float2bfloat16(f0.y);
      u.h[2] = __float2bfloat16(f0.z);
      u.h[3] = __float2bfloat16(f0.w);
      u.h[4] = __float2bfloat16(f1.x);
      u.h[5] = __float2bfloat16(f1.y);
      u.h[6] = __float2bfloat16(f1.z);
      u.h[7] = __float2bfloat16(f1.w);
      *reinterpret_cast<bf16x8*>(adst) = u.v;
    }
    __syncthreads();
#pragma unroll
    for (int kk = 0; kk < 2; ++kk) {
      bf16x8 a[4];
#pragma unroll
      for (int m = 0; m < 4; ++m) {
        const int row = m * 16 + lr;
        a[m] = *reinterpret_cast<const bf16x8*>(
            &As[row * 64 + ((kk * 32 + g * 8) ^ ((row & 7) * 8))]);
      }
#pragma unroll
      for (int n = 0; n < 3; ++n) {
        bf16x8 b = *reinterpret_cast<const bf16x8*>(
            &Bs[(size_t)(wc + n * 16 + lr) * 64 + kk * 32 + g * 8]);
#pragma unroll
        for (int m = 0; m < 4; ++m)
          acc[m][n] =
              __builtin_amdgcn_mfma_f32_16x16x32_bf16(a[m], b, acc[m][n], 0, 0, 0);
      }
    }
  }

#pragma unroll
  for (int n = 0; n < 3; ++n) {
    const int ng = wc + n * 16 + lr;  // 0..383
    const int head = ng >> 7;         // 0:q 1:k 2:v
    const int h = ng & 127;
#pragma unroll
    for (int m = 0; m < 4; ++m) {
#pragma unroll
      for (int r = 0; r < 4; ++r) {
        const int row = m0 + m * 16 + g * 4 + r;  // global token
        const __hip_bfloat16 val = __float2bfloat16(acc[m][n][r]);
        if (head == 0) {
          qb[(size_t)row * H_DIM + h] = val;
        } else if (head == 1) {
          kb[(size_t)row * H_DIM + h] = val;
        } else {
          const int bi = row >> 11;
          const int t = row & (T_SEQ - 1);
          vt[((size_t)bi * H_DIM + h) * T_SEQ + t] = val;
        }
      }
    }
  }
}

// Flash attention, key-parallel, software-pipelined:
// grid = B * T/16 blocks; block = 4 waves, same 16 q rows; wave w handles
// key-blocks kbi ≡ w (mod 4) with private (m,l,O); 2-round LDS tree merge.
// Pipeline: QK^T consumes kf, then kf reloads for next iter; V loads issue
// before softmax so their latency hides under exp/shuffles.
__global__ __launch_bounds__(256) void attn_kernel(
    const __hip_bfloat16* __restrict__ qb, const __hip_bfloat16* __restrict__ kb,
    const __hip_bfloat16* __restrict__ vt, float* __restrict__ out) {
  __shared__ __align__(16) char shraw[2 * 16 * 132 * 4];  // 16.9 KB overlay
  auto Pl = reinterpret_cast<__hip_bfloat16(*)[16][40]>(shraw);  // [4][16][40]
  auto Obuf = reinterpret_cast<float(*)[16][132]>(shraw);        // [2][16][132]
  __shared__ float mbuf[4][16];
  __shared__ float lbuf[4][16];
  const int tid = threadIdx.x;
  const int wave = tid >> 6;
  const int lane = tid & 63;
  const int g = lane >> 4;
  const int lr = lane & 15;
  const int idx = blockIdx.x;
  const int b = idx & 7;
  const int rg = 127 - (idx >> 3);      // heavy row-groups dispatched first
  const int qr0 = rg * 16;

  const __hip_bfloat16* qB = qb + (size_t)b * T_SEQ * H_DIM;
  const __hip_bfloat16* kB = kb + (size_t)b * T_SEQ * H_DIM;
  const __hip_bfloat16* vB = vt + (size_t)b * H_DIM * T_SEQ;

  bf16x8 qf[4];
#pragma unroll
  for (int kt = 0; kt < 4; ++kt)
    qf[kt] = *reinterpret_cast<const bf16x8*>(
        qB + (size_t)(qr0 + lr) * H_DIM + kt * 32 + g * 8);

  f32x4 oacc[8];
#pragma unroll
  for (int i = 0; i < 8; ++i) oacc[i] = f32x4{0.f, 0.f, 0.f, 0.f};
  float mrow[4] = {-1e30f, -1e30f, -1e30f, -1e30f};
  float lrow[4] = {0.f, 0.f, 0.f, 0.f};

  const float scale = 0.08838834764831845f;  // 1/sqrt(128)
  const int nkb = (qr0 + 16 + 31) >> 5;      // 32-key blocks needed

  if (wave < nkb) {
    // ---- preamble: load K fragments for first key-block ----
    bf16x8 kf[8];
    {
      const int s0 = wave * 32;
#pragma unroll
      for (int nt = 0; nt < 2; ++nt)
#pragma unroll
        for (int kt = 0; kt < 4; ++kt)
          kf[nt * 4 + kt] = *reinterpret_cast<const bf16x8*>(
              kB + (size_t)(s0 + nt * 16 + lr) * H_DIM + kt * 32 + g * 8);
    }
    for (int kbi = wave; kbi < nkb; kbi += 4) {
      const int s0 = kbi * 32;
      // ---- QK^T (consumes kf) ----
      f32x4 sacc[2];
      sacc[0] = f32x4{0.f, 0.f, 0.f, 0.f};
      sacc[1] = f32x4{0.f, 0.f, 0.f, 0.f};
#pragma unroll
      for (int nt = 0; nt < 2; ++nt)
#pragma unroll
        for (int kt = 0; kt < 4; ++kt)
          sacc[nt] = __builtin_amdgcn_mfma_f32_16x16x32_bf16(
              qf[kt], kf[nt * 4 + kt], sacc[nt], 0, 0, 0);
      // ---- prefetch K for next iteration (latency hidden by softmax+PV) ----
      {
        const int s0n = (kbi + 4 < nkb) ? (kbi + 4) * 32 : 0;
#pragma unroll
        for (int nt = 0; nt < 2; ++nt)
#pragma unroll
          for (int kt = 0; kt < 4; ++kt)
            kf[nt * 4 + kt] = *reinterpret_cast<const bf16x8*>(
                kB + (size_t)(s0n + nt * 16 + lr) * H_DIM + kt * 32 + g * 8);
      }
      // ---- V loads for current block (latency hidden by softmax) ----
      bf16x8 vf[8];
#pragma unroll
      for (int ht = 0; ht < 8; ++ht)
        vf[ht] = *reinterpret_cast<const bf16x8*>(
            vB + (size_t)(ht * 16 + lr) * T_SEQ + s0 + g * 8);
      // ---- scale + causal mask ----
      float sv[2][4];
#pragma unroll
      for (int nt = 0; nt < 2; ++nt)
#pragma unroll
        for (int r = 0; r < 4; ++r) {
          const int key = s0 + nt * 16 + lr;
          const int qr = qr0 + g * 4 + r;
          const float s = sacc[nt][r] * scale;
          sv[nt][r] = (key > qr) ? -1e30f : s;
        }
      // ---- row max over 32 keys ----
      float pm[4];
#pragma unroll
      for (int r = 0; r < 4; ++r) pm[r] = fmaxf(sv[0][r], sv[1][r]);
#pragma unroll
      for (int m = 1; m < 16; m <<= 1)
#pragma unroll
        for (int r = 0; r < 4; ++r) pm[r] = fmaxf(pm[r], __shfl_xor(pm[r], m, 64));
      // ---- defer-rescale (T13): only rescale when max grew past THR=8 ----
      bool ok = true;
#pragma unroll
      for (int r = 0; r < 4; ++r) ok = ok && (pm[r] <= mrow[r] + 8.f);
      if (!__all((int)ok)) {
#pragma unroll
        for (int r = 0; r < 4; ++r) {
          const float mnew = fmaxf(mrow[r], pm[r]);
          const float corr = __expf(mrow[r] - mnew);
          mrow[r] = mnew;
          lrow[r] *= corr;
#pragma unroll
          for (int ht = 0; ht < 8; ++ht) oacc[ht][r] *= corr;
        }
      }
      // ---- P = exp(S - m), write wave-private LDS tile, row-sum ----
      float rs[4];
#pragma unroll
      for (int r = 0; r < 4; ++r) {
        const float p0 = __expf(sv[0][r] - mrow[r]);
        const float p1 = __expf(sv[1][r] - mrow[r]);
        Pl[wave][g * 4 + r][lr] = __float2bfloat16(p0);
        Pl[wave][g * 4 + r][16 + lr] = __float2bfloat16(p1);
        rs[r] = p0 + p1;
      }
#pragma unroll
      for (int m = 1; m < 16; m <<= 1)
#pragma unroll
        for (int r = 0; r < 4; ++r) rs[r] += __shfl_xor(rs[r], m, 64);
#pragma unroll
      for (int r = 0; r < 4; ++r) lrow[r] += rs[r];
      // ---- PV ----
      bf16x8 pf = *reinterpret_cast<const bf16x8*>(&Pl[wave][lr][g * 8]);
#pragma unroll
      for (int ht = 0; ht < 8; ++ht)
        oacc[ht] = __builtin_amdgcn_mfma_f32_16x16x32_bf16(pf, vf[ht], oacc[ht], 0, 0, 0);
    }
  }

  // ---- cross-wave merge (2-round tree through LDS) ----
  if (lr == 0) {
#pragma unroll
    for (int r = 0; r < 4; ++r) {
      mbuf[wave][g * 4 + r] = mrow[r];
      lbuf[wave][g * 4 + r] = lrow[r];
    }
  }
  __syncthreads();
#pragma unroll
  for (int half = 2; half >= 1; half >>= 1) {
    if (wave >= half && wave < 2 * half) {
#pragma unroll
      for (int ht = 0; ht < 8; ++ht)
#pragma unroll
        for (int r = 0; r < 4; ++r)
          Obuf[wave - half][g * 4 + r][ht * 16 + lr] = oacc[ht][r];
    }
    __syncthreads();
    if (wave < half) {
      float a[4], bt[4];
#pragma unroll
      for (int r = 0; r < 4; ++r) {
        const float mB = mbuf[wave + half][g * 4 + r];
        const float lB = lbuf[wave + half][g * 4 + r];
        const float M = fmaxf(mrow[r], mB);
        a[r] = __expf(mrow[r] - M);
        bt[r] = __expf(mB - M);
        lrow[r] = a[r] * lrow[r] + bt[r] * lB;
        mrow[r] = M;
      }
#pragma unroll
      for (int ht = 0; ht < 8; ++ht)
#pragma unroll
        for (int r = 0; r < 4; ++r)
          oacc[ht][r] =
              a[r] * oacc[ht][r] + bt[r] * Obuf[wave][g * 4 + r][ht * 16 + lr];
      if (lr == 0) {
#pragma unroll
        for (int r = 0; r < 4; ++r) {
          mbuf[wave][g * 4 + r] = mrow[r];
          lbuf[wave][g * 4 + r] = lrow[r];
        }
      }
    }
    __syncthreads();
  }

  // ---- epilogue: wave 0 normalizes and stores fp32 ----
  if (wave == 0) {
#pragma unroll
    for (int ht = 0; ht < 8; ++ht)
#pragma unroll
      for (int r = 0; r < 4; ++r) {
        const int qr = qr0 + g * 4 + r;
        out[((size_t)b * T_SEQ + qr) * H_DIM + ht * 16 + lr] =
            oacc[ht][r] / lrow[r];
      }
  }
}

extern "C" void kernel_launch(void* const* d_in, const int* in_sizes, int n_in,
                              void* d_out, int out_size, void* d_ws, size_t ws_size,
                              hipStream_t stream) {
  const float* x = (const float*)d_in[0];
  const float* Wq = (const float*)d_in[1];
  const float* Wk = (const float*)d_in[2];
  const float* Wv = (const float*)d_in[3];
  float* out = (float*)d_out;

  __hip_bfloat16* Wt = (__hip_bfloat16*)d_ws;
  __hip_bfloat16* qbuf = Wt + (size_t)3 * 128 * 1024;
  __hip_bfloat16* kbuf = qbuf + (size_t)NTOK * H_DIM;
  __hip_bfloat16* vbuf = kbuf + (size_t)NTOK * H_DIM;

  hipLaunchKernelGGL(prep_w_kernel, dim3(384), dim3(256), 0, stream, Wq, Wk, Wv, Wt);
  hipLaunchKernelGGL(proj_kernel, dim3(256), dim3(512), 0, stream, x, Wt, qbuf,
                     kbuf, vbuf);
  hipLaunchKernelGGL(attn_kernel, dim3(1024), dim3(256), 0, stream, qbuf, kbuf,
                     vbuf, out);
}